// Round 3
// baseline (337.257 us; speedup 1.0000x reference)
//
#include <hip/hip_runtime.h>

#define NROW 10000
#define NF 256
#define KF 512
#define MP 10048   // 157*64, padded row/K extent
#define NTILES 157
#define RPB 16     // rows per block in pass1 (10000/16 = 625 exact)

typedef __attribute__((ext_vector_type(8))) short short8x;
typedef __attribute__((ext_vector_type(4))) float f32x4;

__device__ __forceinline__ unsigned short bf16rne(float f){
  unsigned int u = __builtin_bit_cast(unsigned int, f);
  u += 0x7fffu + ((u >> 16) & 1u);   // round-to-nearest-even
  return (unsigned short)(u >> 16);
}

// ---------------- Kernel 0: zero d_out (atomic accumulation target)
__global__ void k_zero(float4* __restrict__ p){
  p[blockIdx.x * 256 + threadIdx.x] = make_float4(0.f, 0.f, 0.f, 0.f);
}

// ---------------- Pass 1 (fused): one sweep of adj does EVERYTHING adj-related
//   adjb[i][k] = bf16(Ahat[i][k])  (diag=1, cols>=10000 zeroed)
//   dinv[i]    = rsqrt(rowsum(Ahat_i))
//   hsT[c][i]  = bf16(dinv[i] * (feat @ W)[i][c])
__global__ __launch_bounds__(256) void k_pass1(const float* __restrict__ feat,
        const float* __restrict__ adj, const float* __restrict__ W,
        float* __restrict__ dinv, unsigned short* __restrict__ adjb,
        unsigned short* __restrict__ hsT){
  __shared__ __align__(16) float fs[RPB][512];   // 32 KB
  __shared__ float deg_part[RPB][4];
  __shared__ float dinv_s[RPB];
  int t = threadIdx.x;
  int i0 = blockIdx.x * RPB;

  // stage RPB feat rows into LDS (used by the h-compute phase below)
  #pragma unroll
  for (int it = 0; it < (RPB*128)/256; ++it){
    int idx = it * 256 + t;
    int r = idx >> 7, c4 = (idx & 127) * 4;
    *(float4*)&fs[r][c4] = *(const float4*)(feat + (size_t)(i0 + r) * KF + c4);
  }

  // stream adj rows: patch diag, row-sum (f32 exact), convert+store bf16
  for (int r = 0; r < RPB; ++r){
    int gr = i0 + r;
    const float* src = adj  + (size_t)gr * NROW;
    unsigned short* dst = adjb + (size_t)gr * MP;
    float s = 0.f;
    for (int idx = t; idx < MP/4; idx += 256){
      int c = idx * 4;
      uint2 o;
      if (c < NROW){
        float4 v = *(const float4*)(src + c);
        if (gr == c    ) v.x = 1.f;
        if (gr == c + 1) v.y = 1.f;
        if (gr == c + 2) v.z = 1.f;
        if (gr == c + 3) v.w = 1.f;
        s += (v.x + v.y) + (v.z + v.w);   // sum of PATCHED row == degree
        o.x = (unsigned int)bf16rne(v.x) | ((unsigned int)bf16rne(v.y) << 16);
        o.y = (unsigned int)bf16rne(v.z) | ((unsigned int)bf16rne(v.w) << 16);
      } else {
        o = make_uint2(0u, 0u);           // K-tail zeros: kill B-tail garbage
      }
      *(uint2*)(dst + c) = o;
    }
    #pragma unroll
    for (int off = 32; off; off >>= 1) s += __shfl_down(s, off);
    if ((t & 63) == 0) deg_part[r][t >> 6] = s;
  }
  __syncthreads();
  if (t < RPB){
    float tot = (deg_part[t][0] + deg_part[t][1]) + (deg_part[t][2] + deg_part[t][3]);
    float dv = tot > 0.f ? rsqrtf(tot) : 0.f;
    dinv[i0 + t] = dv;
    dinv_s[t] = dv;
  }
  __syncthreads();

  // h = feat @ W for these RPB rows; one output column per thread
  float acc[RPB];
  #pragma unroll
  for (int r = 0; r < RPB; ++r) acc[r] = 0.f;
  int c = t;
  for (int k = 0; k < KF; k += 4){
    float w0 = W[(k+0)*NF + c];
    float w1 = W[(k+1)*NF + c];
    float w2 = W[(k+2)*NF + c];
    float w3 = W[(k+3)*NF + c];
    #pragma unroll
    for (int r = 0; r < RPB; ++r){
      float4 f = *(const float4*)&fs[r][k];   // LDS broadcast
      acc[r] = fmaf(f.x, w0, acc[r]);
      acc[r] = fmaf(f.y, w1, acc[r]);
      acc[r] = fmaf(f.z, w2, acc[r]);
      acc[r] = fmaf(f.w, w3, acc[r]);
    }
  }
  unsigned short* hdst = hsT + (size_t)c * MP + i0;
  #pragma unroll
  for (int r = 0; r < RPB; r += 2){
    float a0 = acc[r]   * dinv_s[r];
    float a1 = acc[r+1] * dinv_s[r+1];
    unsigned int u = (unsigned int)bf16rne(a0) | ((unsigned int)bf16rne(a1) << 16);
    *(unsigned int*)(hdst + r) = u;
  }
  // last block zero-fills hsT K-tail rows (avoid 0xAA/NaN poison reaching MFMA)
  if (blockIdx.x == (NROW/RPB) - 1){
    unsigned int* tz = (unsigned int*)(hsT + (size_t)t * MP + NROW);
    #pragma unroll
    for (int m = 0; m < (MP - NROW) / 2; ++m) tz[m] = 0u;
  }
}

// ---------------- Kernel 3: out += adjb @ hs   (K split 4-ways, atomic)
__global__ __launch_bounds__(256, 2) void k_gemm(const unsigned short* __restrict__ adjb,
        const unsigned short* __restrict__ hsT, float* __restrict__ out){
  __shared__ __align__(16) unsigned short Al[64][72];    // +8 pad: 144B stride
  __shared__ __align__(16) unsigned short Bl[256][72];
  int t = threadIdx.x;
  int lane = t & 63, wid = t >> 6;
  int wr = wid >> 1, wc = wid & 1;      // 2x2 waves, wave tile 32x128
  int r0 = blockIdx.x * 64;
  int by = blockIdx.y;                  // K chunks of {40,39,39,39} tiles
  int kt0 = by * 39 + (by > 0 ? 1 : 0);
  int kt1 = (by + 1) * 39 + 1;

  f32x4 acc[2][8];
  #pragma unroll
  for (int a = 0; a < 2; ++a)
    #pragma unroll
    for (int b = 0; b < 8; ++b)
      #pragma unroll
      for (int j = 0; j < 4; ++j) acc[a][b][j] = 0.f;

  int bcol = t >> 3;          // 0..31
  int bko  = (t & 7) * 8;     // 0..56

  for (int kt = kt0; kt < kt1; ++kt){
    int k0 = kt * 64;
    // ---- stage A tile: pure bf16 uint4 copy (2 per thread)
    #pragma unroll
    for (int it = 0; it < 2; ++it){
      int slot = it * 256 + t;
      int row = slot >> 3, off8 = (slot & 7) * 8;
      *(uint4*)&Al[row][off8] =
          *(const uint4*)(adjb + (size_t)(r0 + row) * MP + k0 + off8);
    }
    // ---- stage B tile (bf16 copy from hsT)
    #pragma unroll
    for (int it = 0; it < 8; ++it){
      int cc = it * 32 + bcol;
      *(uint4*)&Bl[cc][bko] = *(const uint4*)(hsT + (size_t)cc * MP + k0 + bko);
    }
    __syncthreads();
    // ---- MFMA: 2x8 fragments of 16x16, K-step 32
    #pragma unroll
    for (int kk = 0; kk < 64; kk += 32){
      short8x a0 = *(const short8x*)&Al[wr*32      + (lane & 15)][kk + (lane >> 4) * 8];
      short8x a1 = *(const short8x*)&Al[wr*32 + 16 + (lane & 15)][kk + (lane >> 4) * 8];
      #pragma unroll
      for (int ni = 0; ni < 8; ++ni){
        short8x b = *(const short8x*)&Bl[wc*128 + ni*16 + (lane & 15)][kk + (lane >> 4) * 8];
        acc[0][ni] = __builtin_amdgcn_mfma_f32_16x16x32_bf16(a0, b, acc[0][ni], 0, 0, 0);
        acc[1][ni] = __builtin_amdgcn_mfma_f32_16x16x32_bf16(a1, b, acc[1][ni], 0, 0, 0);
      }
    }
    __syncthreads();
  }
  // ---- epilogue: atomic accumulate partial K-sums (4 commutative adds/elem)
  #pragma unroll
  for (int mi = 0; mi < 2; ++mi){
    #pragma unroll
    for (int ni = 0; ni < 8; ++ni){
      int gc = wc*128 + ni*16 + (lane & 15);
      #pragma unroll
      for (int j = 0; j < 4; ++j){
        int gr = r0 + wr*32 + mi*16 + (lane >> 4) * 4 + j;
        if (gr < NROW) atomicAdd(out + (size_t)gr * NF + gc, acc[mi][ni][j]);
      }
    }
  }
}

// ---------------- Kernel 4: out = relu(dinv_i * acc + cb + eb), in place
__global__ void k_epi(float* __restrict__ out, const float* __restrict__ dinv,
                      const float* __restrict__ cb, const float* __restrict__ eb){
  int e = (blockIdx.x * 256 + threadIdx.x) * 4;
  int i = e >> 8, c = e & 255;
  float di = dinv[i];
  float4 v = *(float4*)(out + e);
  v.x = fmaxf(fmaf(v.x, di, cb[c+0] + eb[c+0]), 0.f);
  v.y = fmaxf(fmaf(v.y, di, cb[c+1] + eb[c+1]), 0.f);
  v.z = fmaxf(fmaf(v.z, di, cb[c+2] + eb[c+2]), 0.f);
  v.w = fmaxf(fmaf(v.w, di, cb[c+3] + eb[c+3]), 0.f);
  *(float4*)(out + e) = v;
}

extern "C" void kernel_launch(void* const* d_in, const int* in_sizes, int n_in,
                              void* d_out, int out_size, void* d_ws, size_t ws_size,
                              hipStream_t stream){
  const float* feat = (const float*)d_in[0];
  const float* adj  = (const float*)d_in[1];
  const float* W    = (const float*)d_in[2];
  const float* cb   = (const float*)d_in[3];
  const float* eb   = (const float*)d_in[4];
  float* out = (float*)d_out;

  // ws layout: dinv f32[10048] @0 ; hsT bf16[256][10048] @64KB (5.2 MB);
  //            adjb bf16[10048][10048] @8MB (202 MB). Total ~210 MB.
  float* dinv = (float*)d_ws;
  unsigned short* hsT  = (unsigned short*)((char*)d_ws + (64u << 10));
  unsigned short* adjb = (unsigned short*)((char*)d_ws + (8u << 20));

  k_zero <<<(NROW*NF)/1024,  256, 0, stream>>>((float4*)out);
  k_pass1<<<NROW/RPB,        256, 0, stream>>>(feat, adj, W, dinv, adjb, hsT);
  k_gemm <<<dim3(NTILES, 4), 256, 0, stream>>>(adjb, hsT, out);
  k_epi  <<<(NROW*NF)/1024,  256, 0, stream>>>(out, dinv, cb, eb);
}